// Round 10
// baseline (123.711 us; speedup 1.0000x reference)
//
#include <hip/hip_runtime.h>
#include <cstdint>

// y[m][n] = sum_k x[m][k] * (q[n][k] * scale[n]) + bias[n]
// M=32, K=8192, N=8192; int4 nibbles packed 8/int32.
// Verified: fp16 tensors are FLOAT32 on device (in & out); b_packed int32.
// Round-10 design: ONE kernel, ZERO workspace use. Removes the xprep
// dispatch (+~3.5us graph overhead) and any dependency on the harness's
// 43us 268MB ws-poison fill. Structure = round 6's best (256 WGs x 1024
// thr = 4 waves/SIMD, all-B prefetched upfront, A ping-pong), with A read
// directly from f32 x and converted in-register (VALU & A-traffic both
// falsified as bottlenecks in rounds 6/8).
#define M_DIM 32
#define K_DIM 8192
#define N_DIM 8192

typedef _Float16 f16x8 __attribute__((ext_vector_type(8)));
typedef _Float16 f16x2 __attribute__((ext_vector_type(2)));
typedef float    f32x4 __attribute__((ext_vector_type(4)));

__device__ __forceinline__ uint32_t u4e(uint4 v, int t) {
  return (t == 0) ? v.x : (t == 1) ? v.y : (t == 2) ? v.z : v.w;
}

// Magic-bias dequant: dword (8 nibbles) -> 8 exact f16 in [-8,7].
// Element j holds nibble kp[j] = (j>>1)+(j&1)*4; cvtA8 bakes the same
// permutation into the A fragment, so the MFMA dot product is exact.
__device__ __forceinline__ f16x8 dq8(uint32_t w) {
  union { uint32_t u[4]; f16x8 v; } r;
  const uint32_t MASK  = 0x000F000Fu;
  const uint32_t MAGIC = 0x64086408u;                 // f16x2 {1032, 1032}
  const f16x2 magic = __builtin_bit_cast(f16x2, MAGIC);
#pragma unroll
  for (int s = 0; s < 4; ++s) {
    uint32_t t = ((w >> (4 * s)) & MASK) ^ MAGIC;
    f16x2 h = __builtin_bit_cast(f16x2, t) - magic;
    r.u[s] = __builtin_bit_cast(uint32_t, h);
  }
  return r.v;
}

// 8 consecutive f32 -> f16x8 with nibble-pair interleave {x0,x4,x1,x5,...}.
__device__ __forceinline__ f16x8 cvtA8(f32x4 lo, f32x4 hi) {
  f16x8 r;
#pragma unroll
  for (int s = 0; s < 4; ++s) {
    r[2 * s]     = (_Float16)lo[s];
    r[2 * s + 1] = (_Float16)hi[s];
  }
  return r;
}

// 256 WGs x 1024 thr (16 waves, 4 waves/SIMD, 1 WG/CU).
// WG = 32 n-cols x full K; 16 waves k-split 512 k each (16 steps of 32).
// k-map: slot (c,t,quad,j) of wave w: d = w*64 + c*16 + quad*4 + t,
// k = d*8 + kp[j] — same bijection on A and B, exact dot product.
__global__ __launch_bounds__(1024, 4) void qgemm_fused(
    const uint32_t* __restrict__ bq,     // packed int4 [N, K/8]
    const float*    __restrict__ x,      // f32 [32, 8192]
    const float*    __restrict__ sc,     // f32 [8192]
    const float*    __restrict__ bi,     // f32 [8192]
    float*          __restrict__ out) {  // f32 [32, 8192]
  __shared__ float red[16][32][33];      // 67.6 KB, 1 WG/CU

  const int tid  = threadIdx.x;
  const int w    = tid >> 6;             // wave 0..15 -> k0 = w*512
  const int lane = tid & 63;
  const int l16  = lane & 15;
  const int quad = lane >> 4;
  const int n0   = blockIdx.x << 5;      // 32 n per WG

  // B: rows n0+l16, n0+16+l16; uint4 idx = row*256 + w*16 + c*4 + quad.
  // All 8 loads (the WG's whole HBM demand) issued upfront.
  const uint4* bq4 = (const uint4*)bq;
  const uint4* bp0 = bq4 + (size_t)(n0 + l16) * 256 + (w << 4) + quad;
  const uint4* bp1 = bp0 + (size_t)16 * 256;
  uint4 b0[4], b1[4];
#pragma unroll
  for (int c = 0; c < 4; ++c) { b0[c] = bp0[c * 4]; b1[c] = bp1[c * 4]; }

  // A: f32 base = m*8192 + w*512 + quad*32; step s offset = (s>>2)*128+(s&3)*8.
  const float* ap0 = x + (size_t)l16 * K_DIM + (w << 9) + (quad << 5);
  const float* ap1 = ap0 + (size_t)16 * K_DIM;

  f32x4 acc00 = {0.f, 0.f, 0.f, 0.f};
  f32x4 acc01 = {0.f, 0.f, 0.f, 0.f};
  f32x4 acc10 = {0.f, 0.f, 0.f, 0.f};
  f32x4 acc11 = {0.f, 0.f, 0.f, 0.f};

  // Ping-pong A prefetch (4 f32x4 in flight for the next step).
  f32x4 a0l = *(const f32x4*)ap0, a0h = *(const f32x4*)(ap0 + 4);
  f32x4 a1l = *(const f32x4*)ap1, a1h = *(const f32x4*)(ap1 + 4);

#pragma unroll
  for (int s = 0; s < 16; ++s) {         // 16 k-steps of 32
    const int sn   = (s + 1) & 15;       // last iter refetches step 0 (harmless)
    const int offn = ((sn >> 2) << 7) + ((sn & 3) << 3);
    f32x4 n0l = *(const f32x4*)(ap0 + offn), n0h = *(const f32x4*)(ap0 + offn + 4);
    f32x4 n1l = *(const f32x4*)(ap1 + offn), n1h = *(const f32x4*)(ap1 + offn + 4);

    const int c = s >> 2, t = s & 3;
    f16x8 fb0 = dq8(u4e(b0[c], t));
    f16x8 fb1 = dq8(u4e(b1[c], t));
    f16x8 fa0 = cvtA8(a0l, a0h);
    f16x8 fa1 = cvtA8(a1l, a1h);
    acc00 = __builtin_amdgcn_mfma_f32_16x16x32_f16(fa0, fb0, acc00, 0, 0, 0);
    acc01 = __builtin_amdgcn_mfma_f32_16x16x32_f16(fa1, fb0, acc01, 0, 0, 0);
    acc10 = __builtin_amdgcn_mfma_f32_16x16x32_f16(fa0, fb1, acc10, 0, 0, 0);
    acc11 = __builtin_amdgcn_mfma_f32_16x16x32_f16(fa1, fb1, acc11, 0, 0, 0);

    a0l = n0l; a0h = n0h; a1l = n1l; a1h = n1h;
  }

  // C/D layout (verified): n = lane&15 (+16 for b1), m = quad*4 + e (+16).
#pragma unroll
  for (int e = 0; e < 4; ++e) {
    const int mr = (quad << 2) + e;
    red[w][l16][mr]           = acc00[e];
    red[w][l16][mr + 16]      = acc01[e];
    red[w][l16 + 16][mr]      = acc10[e];
    red[w][l16 + 16][mr + 16] = acc11[e];
  }

  __syncthreads();

  // 1024 outputs / 1024 threads: n = tid&31, m = tid>>5.
  const int n = tid & 31;
  const int m = tid >> 5;
  float s = 0.f;
#pragma unroll
  for (int ww = 0; ww < 16; ++ww) s += red[ww][n][m];
  const int gn = n0 + n;
  out[(size_t)m * N_DIM + gn] = fmaf(s, sc[gn], bi[gn]);
}

extern "C" void kernel_launch(void* const* d_in, const int* in_sizes, int n_in,
                              void* d_out, int out_size, void* d_ws, size_t ws_size,
                              hipStream_t stream) {
  const float*    x  = (const float*)d_in[0];     // f32 [32,8192]
  const uint32_t* bq = (const uint32_t*)d_in[1];  // int32 [8192,1024]
  const float*    sc = (const float*)d_in[2];     // f32 [8192]
  const float*    bi = (const float*)d_in[3];     // f32 [8192]
  float*          y  = (float*)d_out;             // f32 [32,8192]

  qgemm_fused<<<N_DIM / 32, 1024, 0, stream>>>(bq, x, sc, bi, y);
}

// Round 11
// 88.837 us; speedup vs baseline: 1.3926x; 1.3926x over previous
//
#include <hip/hip_runtime.h>
#include <cstdint>

// y[m][n] = sum_k x[m][k] * (q[n][k] * scale[n]) + bias[n]
// M=32, K=8192, N=8192; int4 nibbles packed 8/int32.
// Verified: fp16 tensors are FLOAT32 on device (in & out); b_packed int32.
// Round-10 counters: VGPR_Count=32 -> compiler sinks loads, ~3 outstanding
// 16B loads/wave -> 530 GB/s (Little's law). Round-11 fix: stage B via
// async global_load_lds DMA (no VGPRs involved -> scheduler can't
// serialize); 8 issues/thread = whole 128 KB WG demand in flight.
#define M_DIM 32
#define K_DIM 8192
#define N_DIM 8192

typedef _Float16 f16x8 __attribute__((ext_vector_type(8)));
typedef _Float16 f16x2 __attribute__((ext_vector_type(2)));
typedef float    f32x4 __attribute__((ext_vector_type(4)));

#define QSTRIDE 260            // dwords per staged row-chunk (256 + 4 pad)
#define QBLOCK  (32 * QSTRIDE) // dwords per quarter-group
#define SMEM_DW (4 * QBLOCK)   // 33280 dwords = 133120 B total stage

#define GPTR(p) ((const __attribute__((address_space(1))) uint4*)(p))
#define LPTR(p) ((__attribute__((address_space(3))) uint4*)(p))

__device__ __forceinline__ uint32_t u4e(uint4 v, int t) {
  return (t == 0) ? v.x : (t == 1) ? v.y : (t == 2) ? v.z : v.w;
}

// Magic-bias dequant: dword (8 nibbles) -> 8 exact f16 in [-8,7].
// Element j holds nibble kp[j] = (j>>1)+(j&1)*4; xprep bakes the same
// permutation into A, so the MFMA dot product is exact.
__device__ __forceinline__ f16x8 dq8(uint32_t w) {
  union { uint32_t u[4]; f16x8 v; } r;
  const uint32_t MASK  = 0x000F000Fu;
  const uint32_t MAGIC = 0x64086408u;                 // f16x2 {1032, 1032}
  const f16x2 magic = __builtin_bit_cast(f16x2, MAGIC);
#pragma unroll
  for (int s = 0; s < 4; ++s) {
    uint32_t t = ((w >> (4 * s)) & MASK) ^ MAGIC;
    f16x2 h = __builtin_bit_cast(f16x2, t) - magic;
    r.u[s] = __builtin_bit_cast(uint32_t, h);
  }
  return r.v;
}

// -------- x prep: f32 x[32][8192] -> f16 xp[d=k/8][m][8], nibble-pair perm --
__global__ __launch_bounds__(256) void xprep_kernel(
    const float* __restrict__ x, uint4* __restrict__ xp) {
  const int T = blockIdx.x * 256 + threadIdx.x;  // 0..32767
  const int m = T >> 10;                         // 0..31
  const int g = T & 1023;                        // 0..1023
  const f32x4* p = (const f32x4*)(x + (size_t)m * K_DIM + (size_t)g * 8);
  f32x4 lo = p[0], hi = p[1];
  union { uint4 q; f16x8 v; } o;
#pragma unroll
  for (int s = 0; s < 4; ++s) {
    o.v[2 * s]     = (_Float16)lo[s];
    o.v[2 * s + 1] = (_Float16)hi[s];
  }
  xp[(size_t)g * 32 + m] = o.q;
}

// -------- main GEMM: 256 WGs x 1024 thr (16 waves, 4/SIMD, 1 WG/CU) --------
// WG = 32 n x full K; waves k-split 512 each. B: DMA-staged to LDS (linear
// source, quarter-row chunks, wave-uniform dst). A: xp registers (L2).
// k-map: slot (c,t,quad,j) of wave w: d = w*64 + c*16 + quad*4 + t,
// k = d*8 + kp[j] — same bijection on A and B, exact dot product.
__global__ __launch_bounds__(1024, 4) void qgemm_dma(
    const uint32_t* __restrict__ bq,     // packed int4 [N, K/8]
    const uint4*    __restrict__ xp,     // f16 [1024][32][8] (perm'd)
    const float*    __restrict__ sc,     // f32 [8192]
    const float*    __restrict__ bi,     // f32 [8192]
    float*          __restrict__ out) {  // f32 [32, 8192]
  __shared__ uint32_t smem[SMEM_DW];     // B stage; overlaid by red later

  const int tid  = threadIdx.x;
  const int w    = tid >> 6;             // wave 0..15 -> k0 = w*512
  const int lane = tid & 63;
  const int l16  = lane & 15;
  const int quad = lane >> 4;
  const int n0   = blockIdx.x << 5;      // 32 n per WG

  // ---- B staging: source is one contiguous 128 KB block (rows n0..n0+31).
  // Issue i of wave w copies source uint4 [i*1024 + w*64 + lane] ->
  // chunk (row = i*4 + w/4, quarter = w&3), dst = quarter*QBLOCK + row*QSTRIDE
  // (wave-uniform; lane lands at +lane*16 B per the DMA's fixed placement).
  const uint4* bsrc = (const uint4*)bq + (size_t)n0 * 256;
  const int qrt = w & 3;
  const int rw  = w >> 2;
#pragma unroll
  for (int i = 0; i < 8; ++i) {
    const int row = i * 4 + rw;
    __builtin_amdgcn_global_load_lds(
        GPTR(bsrc + i * 1024 + tid),
        LPTR(&smem[qrt * QBLOCK + row * QSTRIDE]),
        16, 0, 0);
  }

  // A pointer (r6-verified): uint4 idx = (w*64 + quad*4 + c*16 + t)*32 + m.
  const uint4* ap = xp + (size_t)(((w << 6) + (quad << 2)) * 32 + l16);
  uint4 a0c = ap[0];                     // issued pre-barrier: arrives
  uint4 a1c = ap[16];                    // during the B drain

  __syncthreads();                       // vmcnt(0): all DMA + A landed

  f32x4 acc00 = {0.f, 0.f, 0.f, 0.f};
  f32x4 acc01 = {0.f, 0.f, 0.f, 0.f};
  f32x4 acc10 = {0.f, 0.f, 0.f, 0.f};
  f32x4 acc11 = {0.f, 0.f, 0.f, 0.f};

  // Fragment pickup: wave w, row r -> dword (w>>2)*QBLOCK + r*QSTRIDE +
  // ((w&3)*16 + c*4 + quad)*4.
  const int bbase = (w >> 2) * QBLOCK + ((w & 3) * 16 + quad) * 4;

#pragma unroll
  for (int c = 0; c < 4; ++c) {
    const int bidx = bbase + c * 16;
    const uint4 bb0 = *(const uint4*)&smem[bidx + l16 * QSTRIDE];
    const uint4 bb1 = *(const uint4*)&smem[bidx + (l16 + 16) * QSTRIDE];
#pragma unroll
    for (int t = 0; t < 4; ++t) {
      const int g   = c * 4 + t;
      const int gn2 = (g + 1) & 15;      // last iter refetches group 0
      const int off = (((gn2 >> 2) << 4) + (gn2 & 3)) << 5;
      uint4 a0n = ap[off];
      uint4 a1n = ap[off + 16];

      f16x8 fb0 = dq8(u4e(bb0, t));
      f16x8 fb1 = dq8(u4e(bb1, t));
      f16x8 fa0 = __builtin_bit_cast(f16x8, a0c);
      f16x8 fa1 = __builtin_bit_cast(f16x8, a1c);
      acc00 = __builtin_amdgcn_mfma_f32_16x16x32_f16(fa0, fb0, acc00, 0, 0, 0);
      acc01 = __builtin_amdgcn_mfma_f32_16x16x32_f16(fa1, fb0, acc01, 0, 0, 0);
      acc10 = __builtin_amdgcn_mfma_f32_16x16x32_f16(fa0, fb1, acc10, 0, 0, 0);
      acc11 = __builtin_amdgcn_mfma_f32_16x16x32_f16(fa1, fb1, acc11, 0, 0, 0);

      a0c = a0n; a1c = a1n;
    }
  }

  __syncthreads();                       // all B reads done; overlay red

  // red[w][n][m], stride 33, overlaid on the stage memory.
  float* red = (float*)smem;
#pragma unroll
  for (int e = 0; e < 4; ++e) {
    const int mr = (quad << 2) + e;
    red[(w * 32 + l16) * 33 + mr]           = acc00[e];
    red[(w * 32 + l16) * 33 + mr + 16]      = acc01[e];
    red[(w * 32 + l16 + 16) * 33 + mr]      = acc10[e];
    red[(w * 32 + l16 + 16) * 33 + mr + 16] = acc11[e];
  }

  __syncthreads();

  // 1024 outputs / 1024 threads: n = tid&31, m = tid>>5.
  const int n = tid & 31;
  const int m = tid >> 5;
  float s = 0.f;
#pragma unroll
  for (int ww = 0; ww < 16; ++ww) s += red[(ww * 32 + n) * 33 + m];
  const int gn = n0 + n;
  out[(size_t)m * N_DIM + gn] = fmaf(s, sc[gn], bi[gn]);
}

// -------- fallback (tiny ws): round-4 known-good direct kernel -------------
__global__ __launch_bounds__(512) void qgemm_direct(
    const uint32_t* __restrict__ bq, const float* __restrict__ x,
    const float* __restrict__ sc, const float* __restrict__ bi,
    float* __restrict__ out) {
  __shared__ float red[8][32][40];
  const int tid  = threadIdx.x;
  const int w    = tid >> 6;
  const int lane = tid & 63;
  const int l16  = lane & 15;
  const int quad = lane >> 4;
  const int n0   = blockIdx.x << 5;

  const uint4* bq4 = (const uint4*)bq;
  const uint4* bp0 = bq4 + (size_t)(n0 + l16) * 256 + (w << 5) + quad;
  const uint4* bp1 = bp0 + (size_t)16 * 256;
  const float* ap0 = x + (size_t)l16 * K_DIM + (w << 10) + (quad << 5);
  const float* ap1 = ap0 + (size_t)16 * K_DIM;

  f32x4 acc00 = {0.f,0.f,0.f,0.f}, acc01 = {0.f,0.f,0.f,0.f};
  f32x4 acc10 = {0.f,0.f,0.f,0.f}, acc11 = {0.f,0.f,0.f,0.f};
#pragma unroll
  for (int c = 0; c < 8; ++c) {
    const uint4 wb0 = bp0[c * 4];
    const uint4 wb1 = bp1[c * 4];
#pragma unroll
    for (int t = 0; t < 4; ++t) {
      const float* a0 = ap0 + c * 128 + t * 8;
      const float* a1 = ap1 + c * 128 + t * 8;
      f32x4 l0 = *(const f32x4*)a0, h0 = *(const f32x4*)(a0 + 4);
      f32x4 l1 = *(const f32x4*)a1, h1 = *(const f32x4*)(a1 + 4);
      f16x8 fa0, fa1;
#pragma unroll
      for (int s = 0; s < 4; ++s) {
        fa0[2*s] = (_Float16)l0[s]; fa0[2*s+1] = (_Float16)h0[s];
        fa1[2*s] = (_Float16)l1[s]; fa1[2*s+1] = (_Float16)h1[s];
      }
      f16x8 fb0 = dq8(u4e(wb0, t));
      f16x8 fb1 = dq8(u4e(wb1, t));
      acc00 = __builtin_amdgcn_mfma_f32_16x16x32_f16(fa0, fb0, acc00, 0, 0, 0);
      acc01 = __builtin_amdgcn_mfma_f32_16x16x32_f16(fa1, fb0, acc01, 0, 0, 0);
      acc10 = __builtin_amdgcn_mfma_f32_16x16x32_f16(fa0, fb1, acc10, 0, 0, 0);
      acc11 = __builtin_amdgcn_mfma_f32_16x16x32_f16(fa1, fb1, acc11, 0, 0, 0);
    }
  }
#pragma unroll
  for (int r = 0; r < 4; ++r) {
    const int mr = (quad << 2) + r;
    red[w][l16][mr]           = acc00[r];
    red[w][l16][mr + 16]      = acc01[r];
    red[w][l16 + 16][mr]      = acc10[r];
    red[w][l16 + 16][mr + 16] = acc11[r];
  }
  __syncthreads();
  const int n  = tid & 31;
  const int mh = tid >> 5;
  float s0 = 0.f, s1 = 0.f;
#pragma unroll
  for (int ww = 0; ww < 8; ++ww) { s0 += red[ww][n][mh]; s1 += red[ww][n][mh+16]; }
  const int gn = n0 + n;
  out[(size_t)mh * N_DIM + gn]        = fmaf(s0, sc[gn], bi[gn]);
  out[(size_t)(mh + 16) * N_DIM + gn] = fmaf(s1, sc[gn], bi[gn]);
}

extern "C" void kernel_launch(void* const* d_in, const int* in_sizes, int n_in,
                              void* d_out, int out_size, void* d_ws, size_t ws_size,
                              hipStream_t stream) {
  const float*    x  = (const float*)d_in[0];     // f32 [32,8192]
  const uint32_t* bq = (const uint32_t*)d_in[1];  // int32 [8192,1024]
  const float*    sc = (const float*)d_in[2];     // f32 [8192]
  const float*    bi = (const float*)d_in[3];     // f32 [8192]
  float*          y  = (float*)d_out;             // f32 [32,8192]

  const size_t XP_BYTES = (size_t)M_DIM * K_DIM * 2;  // 512 KB f16
  if (ws_size >= XP_BYTES) {                          // constant -> graph-safe
    uint4* xp = (uint4*)d_ws;
    xprep_kernel<<<128, 256, 0, stream>>>(x, xp);
    qgemm_dma<<<N_DIM / 32, 1024, 0, stream>>>(bq, xp, sc, bi, y);
  } else {
    qgemm_direct<<<N_DIM / 32, 512, 0, stream>>>(bq, x, sc, bi, y);
  }
}